// Round 1
// baseline (675.171 us; speedup 1.0000x reference)
//
#include <hip/hip_runtime.h>

// Problem constants (fixed by setup_inputs)
#define NT   32768      // B*T tokens
#define NV   32         // V
#define DI   64         // I == H
#define VI   2048       // V*I

typedef __attribute__((ext_vector_type(8)))  short short8;    // 8 bf16 (4 VGPRs)
typedef __attribute__((ext_vector_type(16))) float floatx16;  // MFMA 32x32 acc

#define MFMA32(a,b,c) __builtin_amdgcn_mfma_f32_32x32x16_bf16(a, b, c, 0, 0, 0)

// ---- workspace layout (bytes) ----
// S     : fp32 [NT][64]  (skip|elu(h1))          @ 0         (8,388,608)
// wbuf  : fp32 [NT][32]  (softmax weights)       @ 8388608   (4,194,304)
// WcombT: bf16 [64][2048] (A for weight GEMM)    @ 12582912  (262,144)
// wAv   : bf16 [32][256][88] (augmented A tiles) @ 12845056  (1,441,792)
#define WS_S      0
#define WS_WBUF   8388608
#define WS_WCOMBT 12582912
#define WS_WAV    12845056

static __device__ __forceinline__ unsigned short f2bf(float f) {
    union { float f; unsigned u; } v; v.f = f;
    unsigned r = v.u + 0x7FFFu + ((v.u >> 16) & 1u);   // RNE
    return (unsigned short)(r >> 16);
}
static __device__ __forceinline__ unsigned pk2bf(float lo, float hi) {
    return (unsigned)f2bf(lo) | ((unsigned)f2bf(hi) << 16);
}
static __device__ __forceinline__ float elu1(float v) {
    return (v > 0.f) ? v : (__expf(v) - 1.f);
}

// ============================================================================
// K0: convert + transpose + bias-augment weights to bf16 in ws.
//  WcombT[n][k] = n<32 ? Ws[k][n] : W1[k][n-32]
//  wAv[v][r][c]: r<64: W1a (A[m=h][k=i], col64=b1), r<128: W2a, r>=128: Wga.
//  cols 65..87 zero (K padded to 80 in steps of 16; cols 80..87 never read).
// ============================================================================
__global__ void k0_prep(const float* __restrict__ wg_W1, const float* __restrict__ wg_Ws,
                        const float* __restrict__ v_W1, const float* __restrict__ v_b1,
                        const float* __restrict__ v_W2, const float* __restrict__ v_b2,
                        const float* __restrict__ v_Wg, const float* __restrict__ v_bg,
                        unsigned short* __restrict__ WcombT, unsigned short* __restrict__ wAv) {
    int tid = blockIdx.x * blockDim.x + threadIdx.x;
    int stride = gridDim.x * blockDim.x;
    for (int i = tid; i < 64 * 2048; i += stride) {
        int n = i >> 11, k = i & 2047;
        float val = (n < 32) ? wg_Ws[k * 32 + n] : wg_W1[k * 32 + (n - 32)];
        WcombT[i] = f2bf(val);
    }
    for (int i = tid; i < 32 * 256 * 88; i += stride) {
        int v  = i / (256 * 88);
        int rm = i - v * (256 * 88);
        int r  = rm / 88, c = rm - r * 88;
        float val = 0.f;
        if (r < 64) {
            if (c < 64)       val = v_W1[(v * 64 + c) * 64 + r];
            else if (c == 64) val = v_b1[v * 64 + r];
        } else if (r < 128) {
            int m = r - 64;
            if (c < 64)       val = v_W2[(v * 64 + c) * 64 + m];
            else if (c == 64) val = v_b2[v * 64 + m];
        } else {
            int m = r - 128;
            if (c < 64)       val = v_Wg[(v * 64 + c) * 128 + m];
            else if (c == 64) val = v_bg[v * 128 + m];
        }
        wAv[i] = f2bf(val);
    }
}

// ============================================================================
// K1: S = [skip | elu(h1)] = flat @ [Ws|W1] + [bs|b1], M=32768 K=2048 N=64.
// Transposed: A = WcombT (M=64 outputs), B = x (N=tokens, K-contiguous/lane).
// No LDS staging: B frags straight from global (8 consecutive fp32/lane),
// A frags from L2-resident WcombT. K split 4x across waves; LDS reduce.
// ============================================================================
__launch_bounds__(256, 4)
__global__ void k1_wgemm(const float* __restrict__ x, const unsigned short* __restrict__ WcombT,
                         const float* __restrict__ wg_bs, const float* __restrict__ wg_b1,
                         float* __restrict__ S) {
    __shared__ float Cbuf[4 * 64 * 33];   // [wave][outdim 64][tok 32+pad]
    int tid  = threadIdx.x;
    int wv   = tid >> 6;
    int lane = tid & 63;
    int l31  = lane & 31, s = lane >> 5;
    int tile = blockIdx.x;                             // 1024 tiles x 32 tokens
    long tok = (long)tile * 32 + l31;

    const float*          xrow = x + tok * VI + wv * 512 + s * 8;
    const unsigned short* a0p  = WcombT + (l31)      * 2048 + wv * 512 + s * 8;
    const unsigned short* a1p  = WcombT + (l31 + 32) * 2048 + wv * 512 + s * 8;

    floatx16 acc0 = {}; floatx16 acc1 = {};
    #pragma unroll 4
    for (int ks = 0; ks < 32; ++ks) {
        int ko = ks * 16;
        short8 af0 = *(const short8*)(a0p + ko);
        short8 af1 = *(const short8*)(a1p + ko);
        float4 xa = *(const float4*)(xrow + ko);
        float4 xb = *(const float4*)(xrow + ko + 4);
        union { unsigned u[4]; short8 s8; } bp;
        bp.u[0] = pk2bf(xa.x, xa.y);
        bp.u[1] = pk2bf(xa.z, xa.w);
        bp.u[2] = pk2bf(xb.x, xb.y);
        bp.u[3] = pk2bf(xb.z, xb.w);
        acc0 = MFMA32(af0, bp.s8, acc0);
        acc1 = MFMA32(af1, bp.s8, acc1);
    }
    // partial C -> LDS.  C layout: col=lane&31(tok), row=(reg&3)+8*(reg>>2)+4*s
    float* cb = Cbuf + wv * (64 * 33);
    #pragma unroll
    for (int reg = 0; reg < 16; ++reg) {
        int r0 = (reg & 3) + 8 * (reg >> 2) + 4 * s;
        cb[(r0)*33 + l31]      = acc0[reg];
        cb[(r0 + 32)*33 + l31] = acc1[reg];
    }
    __syncthreads();
    // reduce 4 K-partials + bias/elu epilogue; coalesced stores
    int n  = tid & 63;
    int tb = (tid >> 6) * 8;
    #pragma unroll
    for (int g = 0; g < 8; ++g) {
        int t = tb + g;
        float v = Cbuf[0*2112 + n*33 + t] + Cbuf[1*2112 + n*33 + t]
                + Cbuf[2*2112 + n*33 + t] + Cbuf[3*2112 + n*33 + t];
        if (n < 32) v += wg_bs[n];
        else        v = elu1(v + wg_b1[n - 32]);
        S[((long)tile * 32 + t) * 64 + n] = v;
    }
}

// ============================================================================
// K2: per-token h2 = h1e@W2+b2 ; z = h2@Wg+bg ; w = softmax(LN(skip+glu(z)))
// One wave per token; lanes 0..63 hold S row; shuffles for the tiny matmuls.
// ============================================================================
__launch_bounds__(256, 4)
__global__ void k2_token(const float* __restrict__ S,
                         const float* __restrict__ wg_W2, const float* __restrict__ wg_b2,
                         const float* __restrict__ wg_Wg, const float* __restrict__ wg_bg,
                         const float* __restrict__ wg_gamma, const float* __restrict__ wg_beta,
                         float* __restrict__ wout) {
    int tid = threadIdx.x;
    int wv = tid >> 6, lane = tid & 63;
    int l31 = lane & 31;
    long t = (long)blockIdx.x * 4 + wv;
    float sv = S[t * 64 + lane];
    // h2[j], duplicated on both halves (j = l31)
    float h2 = wg_b2[l31];
    #pragma unroll
    for (int k = 0; k < 32; ++k) {
        float h1e = __shfl(sv, 32 + k);
        h2 += h1e * wg_W2[k * 32 + l31];
    }
    // z[lane] over 64 outputs
    float z = wg_bg[lane];
    #pragma unroll
    for (int k = 0; k < 32; ++k) {
        float hk = __shfl(h2, k);
        z += hk * wg_Wg[k * 64 + lane];
    }
    float za   = __shfl(z, l31);
    float zg   = __shfl(z, l31 + 32);
    float skip = __shfl(sv, l31);
    float y = skip + za / (1.f + __expf(-zg));      // skip + glu(z)
    // LN over 32 (data duplicated with period 32 -> xor masks <=16 are safe)
    float s1 = y;
    #pragma unroll
    for (int m = 1; m <= 16; m <<= 1) s1 += __shfl_xor(s1, m);
    float mean = s1 * (1.f / 32.f);
    float d = y - mean;
    float s2 = d * d;
    #pragma unroll
    for (int m = 1; m <= 16; m <<= 1) s2 += __shfl_xor(s2, m);
    float rinv  = rsqrtf(s2 * (1.f / 32.f) + 1e-5f);
    float logit = d * rinv * wg_gamma[l31] + wg_beta[l31];
    // softmax over 32
    float mx = logit;
    #pragma unroll
    for (int m = 1; m <= 16; m <<= 1) mx = fmaxf(mx, __shfl_xor(mx, m));
    float e = __expf(logit - mx);
    float se = e;
    #pragma unroll
    for (int m = 1; m <= 16; m <<= 1) se += __shfl_xor(se, m);
    if (lane < 32) wout[t * 32 + lane] = e / se;
}

// ============================================================================
// K3: per-variable GRNs + weighted combine (transposed MFMA chain).
// C-layout -> next B-frag via 4 packed shfl_xor(32) + selects per kstep.
// Block: 128 tokens x 16 variables (v-half); 2 blocks/tile accumulate via
// fp32 global atomics (d_out memset to 0 first).
// ============================================================================
static __device__ __forceinline__ void tile_to_bfrags(const float* t16, int sh,
                                                      short8* f0, short8* f1) {
    unsigned P[8];
    #pragma unroll
    for (int i = 0; i < 8; ++i) P[i] = pk2bf(t16[2 * i], t16[2 * i + 1]);
    unsigned X[8];
    #pragma unroll
    for (int i = 0; i < 8; ++i) X[i] = (unsigned)__shfl_xor((int)P[i], 32);
    union { unsigned u[4]; short8 s8; } a, b;
    a.u[0] = sh ? X[2] : P[0];  a.u[1] = sh ? X[3] : P[1];
    a.u[2] = sh ? P[2] : X[0];  a.u[3] = sh ? P[3] : X[1];
    b.u[0] = sh ? X[6] : P[4];  b.u[1] = sh ? X[7] : P[5];
    b.u[2] = sh ? P[6] : X[4];  b.u[3] = sh ? P[7] : X[5];
    *f0 = a.s8; *f1 = b.s8;
}

__launch_bounds__(256, 2)
__global__ void k3_vgrn(const float* __restrict__ x, const unsigned short* __restrict__ wAv,
                        const float* __restrict__ v_gamma, const float* __restrict__ v_beta,
                        const float* __restrict__ wbuf, float* __restrict__ out) {
    __shared__ float xt[128 * 65];                       // fp32 x tile, pad 65 (odd -> conflict-free)
    __shared__ __align__(16) unsigned short wA[256 * 88]; // augmented bf16 A tiles, stride 88 (16B*odd)
    __shared__ float gb[128];                            // gamma/beta interleaved
    int tid  = threadIdx.x;
    int wv   = tid >> 6, lane = tid & 63;
    int l31  = lane & 31, s = lane >> 5;
    int tile = blockIdx.x >> 1;
    int vh   = blockIdx.x & 1;
    int tl   = wv * 32 + l31;                            // token within tile
    long tokg = (long)tile * 128 + tl;

    float outacc[32];
    #pragma unroll
    for (int i = 0; i < 32; ++i) outacc[i] = 0.f;

    // ones B-frag: k=64 (bias col) -> s=0,j=0 only
    union { unsigned u[4]; short8 s8; } onef;
    onef.u[0] = (s == 0) ? 0x00003F80u : 0u;
    onef.u[1] = 0; onef.u[2] = 0; onef.u[3] = 0;

    const unsigned short* wArow = wA + l31 * 88 + s * 8;

    for (int it = 0; it < 16; ++it) {
        int vg = vh * 16 + it;
        __syncthreads();    // protect LDS against previous iteration's readers
        // ---- stage x[tile tokens][v=vg][0..63] fp32 ----
        {
            const float* xsrc = x + ((long)tile * 128 * NV + vg) * DI;
            #pragma unroll
            for (int i2 = 0; i2 < 8; ++i2) {
                int idx = i2 * 256 + tid;
                int row = idx >> 4, c4 = (idx & 15) * 4;
                float4 val = *(const float4*)(xsrc + (long)row * VI + c4);
                float* dst = xt + row * 65 + c4;
                dst[0] = val.x; dst[1] = val.y; dst[2] = val.z; dst[3] = val.w;
            }
        }
        // ---- stage augmented weights (45056 B = 2816 x 16B) ----
        {
            const uint4* wsrc = (const uint4*)(wAv + (long)vg * 256 * 88);
            uint4* wdst = (uint4*)wA;
            #pragma unroll
            for (int i2 = 0; i2 < 11; ++i2) {
                int c = i2 * 256 + tid;
                wdst[c] = wsrc[c];
            }
        }
        if (tid < 128) {
            int h = tid >> 1;
            gb[tid] = (tid & 1) ? v_beta[vg * 64 + h] : v_gamma[vg * 64 + h];
        }
        __syncthreads();

        // ---- x B-frags (4 ksteps of 16) ----
        short8 xb[4];
        const float* xr = xt + tl * 65 + s * 8;
        #pragma unroll
        for (int ks = 0; ks < 4; ++ks) {
            const float* p = xr + ks * 16;
            union { unsigned u[4]; short8 s8; } bp;
            bp.u[0] = pk2bf(p[0], p[1]);
            bp.u[1] = pk2bf(p[2], p[3]);
            bp.u[2] = pk2bf(p[4], p[5]);
            bp.u[3] = pk2bf(p[6], p[7]);
            xb[ks] = bp.s8;
        }
        // ---- H1T = W1a @ [XT;1] ----
        floatx16 h1a0 = {}, h1a1 = {};
        #pragma unroll
        for (int ks = 0; ks < 5; ++ks) {
            short8 b = (ks < 4) ? xb[ks] : onef.s8;
            h1a0 = MFMA32(*(const short8*)(wArow + (0)   * 88 + ks * 16), b, h1a0);
            h1a1 = MFMA32(*(const short8*)(wArow + (32)  * 88 + ks * 16), b, h1a1);
        }
        short8 h1b[4];
        {
            float t16[16];
            #pragma unroll
            for (int r = 0; r < 16; ++r) t16[r] = elu1(h1a0[r]);
            tile_to_bfrags(t16, s, &h1b[0], &h1b[1]);
            #pragma unroll
            for (int r = 0; r < 16; ++r) t16[r] = elu1(h1a1[r]);
            tile_to_bfrags(t16, s, &h1b[2], &h1b[3]);
        }
        // ---- H2T = W2a @ [H1T;1]  (linear, no activation) ----
        floatx16 h2a0 = {}, h2a1 = {};
        #pragma unroll
        for (int ks = 0; ks < 5; ++ks) {
            short8 b = (ks < 4) ? h1b[ks] : onef.s8;
            h2a0 = MFMA32(*(const short8*)(wArow + (64)  * 88 + ks * 16), b, h2a0);
            h2a1 = MFMA32(*(const short8*)(wArow + (96)  * 88 + ks * 16), b, h2a1);
        }
        short8 h2b[4];
        {
            float t16[16];
            #pragma unroll
            for (int r = 0; r < 16; ++r) t16[r] = h2a0[r];
            tile_to_bfrags(t16, s, &h2b[0], &h2b[1]);
            #pragma unroll
            for (int r = 0; r < 16; ++r) t16[r] = h2a1[r];
            tile_to_bfrags(t16, s, &h2b[2], &h2b[3]);
        }
        // ---- GT = Wga @ [H2T;1] : rows 0..63 = a, 64..127 = gate ----
        floatx16 g0 = {}, g1 = {}, g2 = {}, g3 = {};
        #pragma unroll
        for (int ks = 0; ks < 5; ++ks) {
            short8 b = (ks < 4) ? h2b[ks] : onef.s8;
            g0 = MFMA32(*(const short8*)(wArow + (128) * 88 + ks * 16), b, g0);
            g1 = MFMA32(*(const short8*)(wArow + (160) * 88 + ks * 16), b, g1);
            g2 = MFMA32(*(const short8*)(wArow + (192) * 88 + ks * 16), b, g2);
            g3 = MFMA32(*(const short8*)(wArow + (224) * 88 + ks * 16), b, g3);
        }
        // ---- glu + fp32 skip + LN + weighted combine ----
        float y[32];
        #pragma unroll
        for (int r = 0; r < 16; ++r) {
            int hr = (r & 3) + 8 * (r >> 2) + 4 * s;
            float glu0 = g0[r] / (1.f + __expf(-g2[r]));
            float glu1 = g1[r] / (1.f + __expf(-g3[r]));
            y[r]      = xt[tl * 65 + hr]      + glu0;
            y[16 + r] = xt[tl * 65 + 32 + hr] + glu1;
        }
        float s1 = 0.f;
        #pragma unroll
        for (int i = 0; i < 32; ++i) s1 += y[i];
        s1 += __shfl_xor(s1, 32);
        float mean = s1 * (1.f / 64.f);
        float s2 = 0.f;
        #pragma unroll
        for (int i = 0; i < 32; ++i) { float d = y[i] - mean; s2 += d * d; }
        s2 += __shfl_xor(s2, 32);
        float rinv = rsqrtf(s2 * (1.f / 64.f) + 1e-5f);
        float wvv = wbuf[tokg * 32 + vg];
        #pragma unroll
        for (int r = 0; r < 16; ++r) {
            int hr = (r & 3) + 8 * (r >> 2) + 4 * s;
            float pv0 = (y[r]      - mean) * rinv * gb[2*hr]        + gb[2*hr + 1];
            float pv1 = (y[16 + r] - mean) * rinv * gb[2*(hr+32)]   + gb[2*(hr+32) + 1];
            outacc[r]      += wvv * pv0;
            outacc[16 + r] += wvv * pv1;
        }
    }
    // ---- combine the two v-half blocks via atomics ----
    #pragma unroll
    for (int r = 0; r < 16; ++r) {
        int hr = (r & 3) + 8 * (r >> 2) + 4 * s;
        atomicAdd(out + tokg * 64 + hr,      outacc[r]);
        atomicAdd(out + tokg * 64 + 32 + hr, outacc[16 + r]);
    }
}

// ============================================================================
extern "C" void kernel_launch(void* const* d_in, const int* in_sizes, int n_in,
                              void* d_out, int out_size, void* d_ws, size_t ws_size,
                              hipStream_t stream) {
    const float* x        = (const float*)d_in[0];
    const float* wg_W1    = (const float*)d_in[1];
    const float* wg_b1    = (const float*)d_in[2];
    const float* wg_W2    = (const float*)d_in[3];
    const float* wg_b2    = (const float*)d_in[4];
    const float* wg_Wg    = (const float*)d_in[5];
    const float* wg_bg    = (const float*)d_in[6];
    const float* wg_Ws    = (const float*)d_in[7];
    const float* wg_bs    = (const float*)d_in[8];
    const float* wg_gamma = (const float*)d_in[9];
    const float* wg_beta  = (const float*)d_in[10];
    const float* v_W1     = (const float*)d_in[11];
    const float* v_b1     = (const float*)d_in[12];
    const float* v_W2     = (const float*)d_in[13];
    const float* v_b2     = (const float*)d_in[14];
    const float* v_Wg     = (const float*)d_in[15];
    const float* v_bg     = (const float*)d_in[16];
    const float* v_gamma  = (const float*)d_in[17];
    const float* v_beta   = (const float*)d_in[18];
    (void)in_sizes; (void)n_in; (void)ws_size;

    char* ws = (char*)d_ws;
    float* S               = (float*)(ws + WS_S);
    float* wbuf            = (float*)(ws + WS_WBUF);
    unsigned short* WcombT = (unsigned short*)(ws + WS_WCOMBT);
    unsigned short* wAv    = (unsigned short*)(ws + WS_WAV);
    float* out             = (float*)d_out;

    hipMemsetAsync(d_out, 0, (size_t)out_size * sizeof(float), stream);
    k0_prep<<<512, 256, 0, stream>>>(wg_W1, wg_Ws, v_W1, v_b1, v_W2, v_b2, v_Wg, v_bg,
                                     WcombT, wAv);
    k1_wgemm<<<1024, 256, 0, stream>>>(x, WcombT, wg_bs, wg_b1, S);
    k2_token<<<8192, 256, 0, stream>>>(S, wg_W2, wg_b2, wg_Wg, wg_bg, wg_gamma, wg_beta, wbuf);
    k3_vgrn<<<512, 256, 0, stream>>>(x, wAv, v_gamma, v_beta, wbuf, out);
}